// Round 4
// baseline (165.313 us; speedup 1.0000x reference)
//
#include <hip/hip_runtime.h>
#include <math.h>

#define EPSF 1e-5f
#define SINKHORN_ITERS 20
#define C_DIM 4096
#define N_DIM 4

typedef __attribute__((ext_vector_type(4))) float fx4;

// Single fused kernel: one block (512 threads, 8 waves) per batch row b.
// Thread t owns columns {k*2048 + t*4 .. +3} for k=0..1 across all 4
// expansion rows (x read exactly once, held in 32 VGPRs).
//
// The 4x4 sinkhorn + sigmoids are computed redundantly per-thread in
// registers WHILE the 8 x-loads are in flight (~1k VALU cycles hidden under
// ~900-cycle HBM latency) — this removes the separate prep kernel and its
// graph-dependency stall (~5 us).
//
// Plain (cacheable) loads/stores: NT hints removed as an A/B — the 6.3 TB/s
// copy ceiling and 7.0 TB/s fills both use the normal path, and this kernel
// has zero L2 reuse, so NT can only be neutral-or-worse.
__global__ __launch_bounds__(512, 4)
void fused_kernel(const float* __restrict__ x,
                  const float* __restrict__ w,
                  const float* __restrict__ H_pre,
                  const float* __restrict__ H_post,
                  const float* __restrict__ H_res,
                  float* __restrict__ out) {
    const int b = blockIdx.x;
    const int t = threadIdx.x;

    const size_t base = (size_t)b * (N_DIM * C_DIM);
    const int c0 = t * 4;

    // ---- issue all 8 x loads first (they stream while we do sinkhorn) ----
    fx4 xv[4][2];   // [row i][chunk k]
    #pragma unroll
    for (int i = 0; i < 4; ++i)
        #pragma unroll
        for (int k = 0; k < 2; ++k)
            xv[i][k] = *reinterpret_cast<const fx4*>(
                x + base + i * C_DIM + k * 2048 + c0);

    // ---- tiny prep in registers (uniform across all threads) ----
    float M[4][4];
    #pragma unroll
    for (int i = 0; i < 4; ++i)
        #pragma unroll
        for (int j = 0; j < 4; ++j)
            M[i][j] = __expf(H_res[i * 4 + j]);
    for (int it = 0; it < SINKHORN_ITERS; ++it) {
        #pragma unroll
        for (int i = 0; i < 4; ++i) {       // row normalize (axis=1)
            float s = 1.0f / (M[i][0] + M[i][1] + M[i][2] + M[i][3] + EPSF);
            M[i][0] *= s; M[i][1] *= s; M[i][2] *= s; M[i][3] *= s;
        }
        #pragma unroll
        for (int j = 0; j < 4; ++j) {       // col normalize (axis=0)
            float s = 1.0f / (M[0][j] + M[1][j] + M[2][j] + M[3][j] + EPSF);
            M[0][j] *= s; M[1][j] *= s; M[2][j] *= s; M[3][j] *= s;
        }
    }
    const float p0 = 1.0f / (1.0f + __expf(-H_pre[0]));
    const float p1 = 1.0f / (1.0f + __expf(-H_pre[1]));
    const float p2 = 1.0f / (1.0f + __expf(-H_pre[2]));
    const float p3 = 1.0f / (1.0f + __expf(-H_pre[3]));
    float po[4];
    #pragma unroll
    for (int i = 0; i < 4; ++i)
        po[i] = 2.0f / (1.0f + __expf(-H_post[i]));

    // ---- aggregate + sum of squares ----
    float ss = 0.0f;
    #pragma unroll
    for (int k = 0; k < 2; ++k) {
        fx4 a = p0 * xv[0][k] + p1 * xv[1][k] + p2 * xv[2][k] + p3 * xv[3][k];
        ss += a.x * a.x + a.y * a.y + a.z * a.z + a.w * a.w;
    }

    // wave64 reduce -> 8 partials -> every thread sums them (one barrier).
    // At the barrier all loads are consumed and no stores issued, so the
    // compiler's vmcnt(0) drain is free.
    #pragma unroll
    for (int off = 32; off > 0; off >>= 1)
        ss += __shfl_down(ss, off, 64);
    __shared__ float sp[8];
    if ((t & 63) == 0) sp[t >> 6] = ss;
    __syncthreads();
    const float tot = sp[0] + sp[1] + sp[2] + sp[3]
                    + sp[4] + sp[5] + sp[6] + sp[7];
    const float inv = 1.0f / sqrtf(tot * (1.0f / (float)C_DIM) + EPSF);

    // ---- output: out[b,i,c] = sum_j M[i][j] x[b,j,c] + po_i*(agg*inv*w) ----
    #pragma unroll
    for (int k = 0; k < 2; ++k) {
        fx4 wv = *reinterpret_cast<const fx4*>(w + k * 2048 + c0);  // L2-hot
        fx4 a = p0 * xv[0][k] + p1 * xv[1][k] + p2 * xv[2][k] + p3 * xv[3][k];
        fx4 nw = a * inv * wv;
        #pragma unroll
        for (int i = 0; i < 4; ++i) {
            fx4 o = M[i][0] * xv[0][k] + M[i][1] * xv[1][k]
                  + M[i][2] * xv[2][k] + M[i][3] * xv[3][k]
                  + po[i] * nw;
            *reinterpret_cast<fx4*>(out + base + i * C_DIM + k * 2048 + c0) = o;
        }
    }
}

extern "C" void kernel_launch(void* const* d_in, const int* in_sizes, int n_in,
                              void* d_out, int out_size, void* d_ws, size_t ws_size,
                              hipStream_t stream) {
    const float* x      = (const float*)d_in[0];
    const float* w      = (const float*)d_in[1];
    const float* H_pre  = (const float*)d_in[2];
    const float* H_post = (const float*)d_in[3];
    const float* H_res  = (const float*)d_in[4];
    float* out = (float*)d_out;

    const int B = in_sizes[0] / (N_DIM * C_DIM);  // 4096

    fused_kernel<<<B, 512, 0, stream>>>(x, w, H_pre, H_post, H_res, out);
}

// Round 5
// 102.827 us; speedup vs baseline: 1.6077x; 1.6077x over previous
//
#include <hip/hip_runtime.h>
#include <math.h>

#define EPSF 1e-5f
#define SINKHORN_ITERS 20
#define C_DIM 4096
#define N_DIM 4

typedef __attribute__((ext_vector_type(4))) float fx4;

// Kernel 1: tiny prep — sigmoids + sinkhorn on 4x4. params layout:
// [0..3] = sigmoid(H_pre), [4..7] = 2*sigmoid(H_post), [8..23] = M row-major.
// R4 lesson: this MUST stay a separate 1-thread kernel — folding it into the
// fused kernel made every wave pay a ~3.2k-cycle serial rcp chain (VALUBusy
// 97%, +50us).
__global__ void prep_kernel(const float* __restrict__ H_pre,
                            const float* __restrict__ H_post,
                            const float* __restrict__ H_res,
                            float* __restrict__ params) {
    if (threadIdx.x != 0 || blockIdx.x != 0) return;
    float M[4][4];
    for (int i = 0; i < 4; ++i)
        for (int j = 0; j < 4; ++j)
            M[i][j] = expf(H_res[i * 4 + j]);
    for (int it = 0; it < SINKHORN_ITERS; ++it) {
        for (int i = 0; i < 4; ++i) {       // row normalize (axis=1)
            float s = M[i][0] + M[i][1] + M[i][2] + M[i][3] + EPSF;
            M[i][0] /= s; M[i][1] /= s; M[i][2] /= s; M[i][3] /= s;
        }
        for (int j = 0; j < 4; ++j) {       // col normalize (axis=0)
            float s = M[0][j] + M[1][j] + M[2][j] + M[3][j] + EPSF;
            M[0][j] /= s; M[1][j] /= s; M[2][j] /= s; M[3][j] /= s;
        }
    }
    for (int i = 0; i < 4; ++i) {
        params[i]     = 1.0f / (1.0f + expf(-H_pre[i]));
        params[4 + i] = 2.0f / (1.0f + expf(-H_post[i]));
    }
    for (int i = 0; i < 4; ++i)
        for (int j = 0; j < 4; ++j)
            params[8 + i * 4 + j] = M[i][j];
}

// Kernel 2: one block (512 threads, 8 waves) per batch row b.
// Thread t owns columns {k*2048 + t*4 .. +3} for k=0..1 across all 4
// expansion rows (x read exactly once, held in 32 VGPRs). Single
// __syncthreads for the RMS reduce.
//
// Cache policy (R4 counter evidence): plain cacheable LOADS — x is never
// mutated, so the 256MB Infinity Cache retains ~half of it across graph
// replays (R4 FETCH_SIZE=128MB < 256MB input). Nontemporal STORES — the
// 256MB output stream must not evict x from L3.
__global__ __launch_bounds__(512, 8)
void fused_kernel(const float* __restrict__ x,
                  const float* __restrict__ w,
                  const float* __restrict__ params,
                  float* __restrict__ out) {
    const int b = blockIdx.x;
    const int t = threadIdx.x;

    // uniform indices -> scalar (s_load) broadcast, zero VGPR cost
    const float p0 = params[0], p1 = params[1], p2 = params[2], p3 = params[3];

    const size_t base = (size_t)b * (N_DIM * C_DIM);
    const int c0 = t * 4;

    // Load x[b, i, k*2048 + c0 .. +3] — 8 float4 in flight, cacheable.
    fx4 xv[4][2];   // [row i][chunk k]
    #pragma unroll
    for (int i = 0; i < 4; ++i)
        #pragma unroll
        for (int k = 0; k < 2; ++k)
            xv[i][k] = *reinterpret_cast<const fx4*>(
                x + base + i * C_DIM + k * 2048 + c0);

    // aggregate + sum of squares (agg recomputed later; only ss kept)
    float ss = 0.0f;
    #pragma unroll
    for (int k = 0; k < 2; ++k) {
        fx4 a = p0 * xv[0][k] + p1 * xv[1][k] + p2 * xv[2][k] + p3 * xv[3][k];
        ss += a.x * a.x + a.y * a.y + a.z * a.z + a.w * a.w;
    }

    // wave64 reduce -> 8 partials -> every thread sums them (one barrier)
    #pragma unroll
    for (int off = 32; off > 0; off >>= 1)
        ss += __shfl_down(ss, off, 64);
    __shared__ float sp[8];
    if ((t & 63) == 0) sp[t >> 6] = ss;
    __syncthreads();
    const float tot = sp[0] + sp[1] + sp[2] + sp[3]
                    + sp[4] + sp[5] + sp[6] + sp[7];
    const float inv = 1.0f / sqrtf(tot * (1.0f / (float)C_DIM) + EPSF);

    // output: out[b,i,c] = sum_j M[i][j] x[b,j,c] + post_i * (agg*inv*w)
    #pragma unroll
    for (int k = 0; k < 2; ++k) {
        fx4 wv = *reinterpret_cast<const fx4*>(w + k * 2048 + c0);  // L2-hot
        fx4 a = p0 * xv[0][k] + p1 * xv[1][k] + p2 * xv[2][k] + p3 * xv[3][k];
        fx4 nw = a * inv * wv;
        #pragma unroll
        for (int i = 0; i < 4; ++i) {
            const float m0 = params[8 + i * 4 + 0];
            const float m1 = params[8 + i * 4 + 1];
            const float m2 = params[8 + i * 4 + 2];
            const float m3 = params[8 + i * 4 + 3];
            const float po = params[4 + i];
            fx4 o = m0 * xv[0][k] + m1 * xv[1][k] + m2 * xv[2][k] + m3 * xv[3][k]
                  + po * nw;
            __builtin_nontemporal_store(
                o, reinterpret_cast<fx4*>(out + base + i * C_DIM + k * 2048 + c0));
        }
    }
}

extern "C" void kernel_launch(void* const* d_in, const int* in_sizes, int n_in,
                              void* d_out, int out_size, void* d_ws, size_t ws_size,
                              hipStream_t stream) {
    const float* x      = (const float*)d_in[0];
    const float* w      = (const float*)d_in[1];
    const float* H_pre  = (const float*)d_in[2];
    const float* H_post = (const float*)d_in[3];
    const float* H_res  = (const float*)d_in[4];
    float* out    = (float*)d_out;
    float* params = (float*)d_ws;

    const int B = in_sizes[0] / (N_DIM * C_DIM);  // 4096

    prep_kernel<<<1, 64, 0, stream>>>(H_pre, H_post, H_res, params);
    fused_kernel<<<B, 512, 0, stream>>>(x, w, params, out);
}